// Round 9
// baseline (90.628 us; speedup 1.0000x reference)
//
#include <hip/hip_runtime.h>

#define N_NODES 100000
#define N_EDGES 1600000
#define F 64
#define NPB 128                              // nodes per bucket (dst>>7)
#define NB ((N_NODES + NPB - 1) / NPB)       // 782 buckets
#define CAP 2432                             // bucket capacity (mean 2048, +8.5 sigma)
#define BLK_E 8192                           // edges per split block
#define NSPLIT ((N_EDGES + BLK_E - 1) / BLK_E)   // 196
#define GEMM_ROWS 64                         // rows per gemm block
#define NGEMM ((N_NODES + GEMM_ROWS - 1) / GEMM_ROWS)  // 1563
#define SMEM_BYTES (NB * 4)                  // split role LDS: hist only (3128 B)

typedef unsigned short ushort_t;
typedef unsigned int uint_t;
using bf16x8 = __attribute__((ext_vector_type(8))) short;
using f32x4  = __attribute__((ext_vector_type(4))) float;

// round-to-nearest-even float -> bf16 bits
__device__ __forceinline__ ushort_t f2bf(float x) {
    uint_t u = __float_as_uint(x);
    u += 0x7FFFu + ((u >> 16) & 1u);
    return (ushort_t)(u >> 16);
}
__device__ __forceinline__ float bflo(uint_t v) {   // low bf16 of a uint
    return __uint_as_float(v << 16);
}
__device__ __forceinline__ float bfhi(uint_t v) {   // high bf16 of a uint
    return __uint_as_float(v & 0xFFFF0000u);
}

// ---------------------------------------------------------------------------
// Fused kernel: blocks [0, NSPLIT) do the edge bucket-split; blocks
// [NSPLIT, NSPLIT+NGEMM) do hn = bf16((h@W)*norm) via MFMA. LDS = 3.2 KB
// (hist only; split re-reads its L2-hot edge chunk instead of staging),
// so occupancy is wave-capped (~8 blocks/CU), not LDS-capped.
//
// Packed record: (src << 7) | (dst & 127).
//
// MFMA 16x16x32 bf16 layouts (m89-verified D; standard A/B):
//   A: m = lane&15,  k = (lane>>4)*8 + j   (j = 0..7)
//   B: n = lane&15,  k = (lane>>4)*8 + j
//   D: n = lane&15,  m = (lane>>4)*4 + reg
// ---------------------------------------------------------------------------
__launch_bounds__(256)
__global__ void gemm_split_kernel(const float* __restrict__ h,
                                  const float* __restrict__ w,
                                  const float* __restrict__ norm,
                                  ushort_t* __restrict__ hn,
                                  const int* __restrict__ src,
                                  const int* __restrict__ dst,
                                  int* __restrict__ bcnt,
                                  uint_t* __restrict__ bpack) {
    __shared__ __align__(16) int hist[NB];
    const int t = threadIdx.x;

    if (blockIdx.x < NSPLIT) {
        // ---- split role: histogram (dst only) -> bulk reserve -> place ----
        const int e0 = blockIdx.x * BLK_E;
        const int n  = min(BLK_E, N_EDGES - e0);

        for (int i = t; i < NB; i += 256) hist[i] = 0;
        __syncthreads();

        for (int i = t; i < n; i += 256)
            atomicAdd(&hist[dst[e0 + i] >> 7], 1);
        __syncthreads();

        for (int i = t; i < NB; i += 256) {
            const int c = hist[i];
            hist[i] = c ? atomicAdd(&bcnt[i], c) : 0;
        }
        __syncthreads();

        for (int i = t; i < n; i += 256) {
            const int d = dst[e0 + i];          // L2-hot re-read
            const int s = src[e0 + i];
            const int b = d >> 7;
            const int p = atomicAdd(&hist[b], 1);
            if (p < CAP)
                bpack[(size_t)b * CAP + p] = ((uint_t)s << 7) | (uint_t)(d & 127);
        }
    } else {
        // ---- gemm role: MFMA, 4 waves x 16 cols, 4 row-tiles per wave ----
        const int gb  = blockIdx.x - NSPLIT;
        const int wv  = t >> 6;        // wave 0..3 -> cols 16*wv..16*wv+15
        const int l   = t & 63;
        const int lr  = l & 15;
        const int lk  = l >> 4;
        const int col = wv * 16 + lr;
        const int r0  = gb * GEMM_ROWS;

        bf16x8 b0, b1;
#pragma unroll
        for (int j = 0; j < 8; ++j) {
            b0[j] = (short)f2bf(w[(lk * 8 + j) * F + col]);
            b1[j] = (short)f2bf(w[(32 + lk * 8 + j) * F + col]);
        }

#pragma unroll
        for (int tt = 0; tt < 4; ++tt) {
            const int r  = r0 + tt * 16 + lr;
            const int rl = min(r, N_NODES - 1);
            const float4 ha0 = *(const float4*)(h + (size_t)rl * F + lk * 8);
            const float4 ha1 = *(const float4*)(h + (size_t)rl * F + lk * 8 + 4);
            const float4 hb0 = *(const float4*)(h + (size_t)rl * F + 32 + lk * 8);
            const float4 hb1 = *(const float4*)(h + (size_t)rl * F + 32 + lk * 8 + 4);
            bf16x8 a0, a1;
            a0[0] = (short)f2bf(ha0.x); a0[1] = (short)f2bf(ha0.y);
            a0[2] = (short)f2bf(ha0.z); a0[3] = (short)f2bf(ha0.w);
            a0[4] = (short)f2bf(ha1.x); a0[5] = (short)f2bf(ha1.y);
            a0[6] = (short)f2bf(ha1.z); a0[7] = (short)f2bf(ha1.w);
            a1[0] = (short)f2bf(hb0.x); a1[1] = (short)f2bf(hb0.y);
            a1[2] = (short)f2bf(hb0.z); a1[3] = (short)f2bf(hb0.w);
            a1[4] = (short)f2bf(hb1.x); a1[5] = (short)f2bf(hb1.y);
            a1[6] = (short)f2bf(hb1.z); a1[7] = (short)f2bf(hb1.w);

            f32x4 acc = {0.f, 0.f, 0.f, 0.f};
            acc = __builtin_amdgcn_mfma_f32_16x16x32_bf16(a0, b0, acc, 0, 0, 0);
            acc = __builtin_amdgcn_mfma_f32_16x16x32_bf16(a1, b1, acc, 0, 0, 0);

#pragma unroll
            for (int i2 = 0; i2 < 4; ++i2) {
                const int m = r0 + tt * 16 + lk * 4 + i2;
                if (m < N_NODES)
                    hn[(size_t)m * F + col] = f2bf(acc[i2] * norm[m]);
            }
        }
    }
}

// ---------------------------------------------------------------------------
// Fused build+gather: one block (512 thr) per bucket of 128 dst nodes.
// Stage records in LDS -> LDS count/scan -> bucket-LOCAL edge list in LDS ->
// register-accumulating gather (wave per node), fused post-scale, one store.
// ---------------------------------------------------------------------------
__launch_bounds__(512)
__global__ void gather_build_kernel(const int* __restrict__ bcnt,
                                    const uint_t* __restrict__ bpack,
                                    const ushort_t* __restrict__ hn,
                                    const float* __restrict__ norm,
                                    float* __restrict__ out) {
    __shared__ uint_t ebuf[CAP];     // 9.7 KB packed records
    __shared__ int    lsrc[CAP];     // 9.7 KB bucket-local edge list (src ids)
    __shared__ int    cnt[NPB];
    __shared__ int    beg[NPB];
    __shared__ int    cur[NPB];
    __shared__ int    sc[NPB];

    const int b = blockIdx.x;
    const int t = threadIdx.x;
    const int n = min(bcnt[b], CAP);

    if (t < NPB) cnt[t] = 0;
    __syncthreads();

    for (int i = t; i < n; i += 512) {
        const uint_t v = bpack[(size_t)b * CAP + i];
        ebuf[i] = v;
        atomicAdd(&cnt[v & 127u], 1);
    }
    __syncthreads();

    // Hillis-Steele inclusive scan over 128 counts (threads t<128 active)
    int acc = (t < NPB) ? cnt[t] : 0;
    if (t < NPB) sc[t] = acc;
    __syncthreads();
#pragma unroll
    for (int off = 1; off < NPB; off <<= 1) {
        int add = 0;
        if (t < NPB && t >= off) add = sc[t - off];
        __syncthreads();
        if (t < NPB) { acc += add; sc[t] = acc; }
        __syncthreads();
    }
    if (t < NPB) {
        const int e = acc - cnt[t];
        beg[t] = e;
        cur[t] = e;
    }
    __syncthreads();

    for (int i = t; i < n; i += 512) {
        const uint_t e = ebuf[i];
        const int p = atomicAdd(&cur[e & 127u], 1);
        lsrc[p] = (int)(e >> 7);
    }
    __syncthreads();

    // gather: wave w handles local nodes w, w+8, ...
    const int wave = t >> 6;
    const int lane = t & 63;
    const int s = lane >> 4;   // edge slot
    const int c = lane & 15;   // col group: cols 4c..4c+3

    for (int ld = wave; ld < NPB; ld += 8) {
        const int node = b * NPB + ld;
        if (node >= N_NODES) break;

        const int bg = beg[ld];
        const int en = bg + cnt[ld];

        float a0 = 0.f, a1 = 0.f, a2 = 0.f, a3 = 0.f;
        int i = bg;
        for (; i + 7 < en; i += 8) {
            const int sA = lsrc[i + s];
            const int sB = lsrc[i + 4 + s];
            const uint2 vA = *(const uint2*)(hn + (size_t)sA * F + 4 * c);
            const uint2 vB = *(const uint2*)(hn + (size_t)sB * F + 4 * c);
            a0 += bflo(vA.x) + bflo(vB.x);
            a1 += bfhi(vA.x) + bfhi(vB.x);
            a2 += bflo(vA.y) + bflo(vB.y);
            a3 += bfhi(vA.y) + bfhi(vB.y);
        }
        for (; i < en; i += 4) {
            const int e = i + s;
            if (e < en) {
                const int sv = lsrc[e];
                const uint2 v = *(const uint2*)(hn + (size_t)sv * F + 4 * c);
                a0 += bflo(v.x);
                a1 += bfhi(v.x);
                a2 += bflo(v.y);
                a3 += bfhi(v.y);
            }
        }

        a0 += __shfl_xor(a0, 16); a0 += __shfl_xor(a0, 32);
        a1 += __shfl_xor(a1, 16); a1 += __shfl_xor(a1, 32);
        a2 += __shfl_xor(a2, 16); a2 += __shfl_xor(a2, 32);
        a3 += __shfl_xor(a3, 16); a3 += __shfl_xor(a3, 32);

        if (s == 0) {
            const float nv = norm[node];
            float4 r;
            r.x = a0 * nv; r.y = a1 * nv; r.z = a2 * nv; r.w = a3 * nv;
            *(float4*)(out + (size_t)node * F + 4 * c) = r;
        }
    }
}

extern "C" void kernel_launch(void* const* d_in, const int* in_sizes, int n_in,
                              void* d_out, int out_size, void* d_ws, size_t ws_size,
                              hipStream_t stream) {
    const float* h    = (const float*)d_in[0];
    const float* w    = (const float*)d_in[1];
    const float* norm = (const float*)d_in[2];
    const int*   src  = (const int*)d_in[3];
    const int*   dst  = (const int*)d_in[4];
    float* out = (float*)d_out;

    // Workspace layout (256-aligned chunks), total ~20.4 MB:
    char* ws = (char*)d_ws;
    ushort_t* hn  = (ushort_t*)ws;                       // 12,800,000 B
    uint_t* bpack = (uint_t*)(ws + 12800000);            //  7,607,296 B (NB*CAP*4)
    int* bcnt     = (int*)(ws + 12800000 + 7607296);     //      3,328 B

    hipMemsetAsync(bcnt, 0, NB * sizeof(int), stream);

    gemm_split_kernel<<<NSPLIT + NGEMM, 256, 0, stream>>>(
        h, w, norm, hn, src, dst, bcnt, bpack);

    gather_build_kernel<<<NB, 512, 0, stream>>>(bcnt, bpack, hn, norm, out);
}

// Round 10
// 84.095 us; speedup vs baseline: 1.0777x; 1.0777x over previous
//
#include <hip/hip_runtime.h>

#define N_NODES 100000
#define N_EDGES 1600000
#define F 64
#define NPB 128                              // nodes per bucket (dst>>7)
#define NB ((N_NODES + NPB - 1) / NPB)       // 782 buckets
#define CAP 2432                             // bucket capacity (mean 2048, +8.5 sigma)
#define BLK_E 8192                           // edges per split block (= segment size)
#define NSPLIT ((N_EDGES + BLK_E - 1) / BLK_E)   // 196
#define GEMM_ROWS 64                         // rows per gemm block
#define NGEMM ((N_NODES + GEMM_ROWS - 1) / GEMM_ROWS)  // 1563

typedef unsigned short ushort_t;
typedef unsigned int uint_t;
using bf16x8 = __attribute__((ext_vector_type(8))) short;
using f32x4  = __attribute__((ext_vector_type(4))) float;

// round-to-nearest-even float -> bf16 bits
__device__ __forceinline__ ushort_t f2bf(float x) {
    uint_t u = __float_as_uint(x);
    u += 0x7FFFu + ((u >> 16) & 1u);
    return (ushort_t)(u >> 16);
}
__device__ __forceinline__ float bflo(uint_t v) {   // low bf16 of a uint
    return __uint_as_float(v << 16);
}
__device__ __forceinline__ float bfhi(uint_t v) {   // high bf16 of a uint
    return __uint_as_float(v & 0xFFFF0000u);
}

// ---------------------------------------------------------------------------
// Fused kernel: blocks [0, NSPLIT) counting-sort their own 8192-edge chunk by
// bucket and write records CONTIGUOUSLY into a private segment (single-writer
// lines -> writeback amplification ~1.0; NO global atomics anywhere), plus a
// 783-entry ushort offset row. Blocks [NSPLIT, ..) do hn = bf16((h@W)*norm)
// via MFMA.
//
// Packed record: (src << 7) | (dst & 127).
//
// MFMA 16x16x32 bf16 layouts (m89-verified D; standard A/B):
//   A: m = lane&15,  k = (lane>>4)*8 + j   (j = 0..7)
//   B: n = lane&15,  k = (lane>>4)*8 + j
//   D: n = lane&15,  m = (lane>>4)*4 + reg
// ---------------------------------------------------------------------------
__launch_bounds__(256)
__global__ void gemm_split_kernel(const float* __restrict__ h,
                                  const float* __restrict__ w,
                                  const float* __restrict__ norm,
                                  ushort_t* __restrict__ hn,
                                  const int* __restrict__ src,
                                  const int* __restrict__ dst,
                                  ushort_t* __restrict__ offtab,
                                  uint_t* __restrict__ seg) {
    __shared__ int hist[1024];   // bucket counts (zero-padded past NB)
    __shared__ int cur[NB + 2];  // placement cursors
    __shared__ int sc[256];      // scan scratch
    const int t = threadIdx.x;

    if (blockIdx.x < NSPLIT) {
        // ---- split role: histogram -> scan -> offsets -> ordered place ----
        const int e0 = blockIdx.x * BLK_E;
        const int n  = min(BLK_E, N_EDGES - e0);

        for (int i = t; i < 1024; i += 256) hist[i] = 0;
        __syncthreads();

        for (int i = t; i < n; i += 256)
            atomicAdd(&hist[dst[e0 + i] >> 7], 1);
        __syncthreads();

        // exclusive scan over 783 bins (4 bins/thread, padded to 1024)
        const int b0i = 4 * t;
        int v0 = hist[b0i], v1 = hist[b0i + 1], v2 = hist[b0i + 2], v3 = hist[b0i + 3];
        const int ssum = v0 + v1 + v2 + v3;
        sc[t] = ssum;
        __syncthreads();
        int acc = ssum;
#pragma unroll
        for (int off = 1; off < 256; off <<= 1) {
            const int add = (t >= off) ? sc[t - off] : 0;
            __syncthreads();
            acc += add;
            sc[t] = acc;
            __syncthreads();
        }
        int run = acc - ssum;
        ushort_t* offrow = offtab + (size_t)blockIdx.x * (NB + 1);
        const int vj[4] = {v0, v1, v2, v3};
#pragma unroll
        for (int j = 0; j < 4; ++j) {
            const int bin = b0i + j;
            if (bin < NB) {
                offrow[bin] = (ushort_t)run;
                cur[bin] = run;
            } else if (bin == NB) {
                offrow[NB] = (ushort_t)run;   // == n
            }
            run += vj[j];
        }
        __syncthreads();

        // place (edge chunk re-read is L2-hot; stores land in the block's
        // private 32 KB segment -> full-line writeback)
        uint_t* myseg = seg + (size_t)blockIdx.x * BLK_E;
        for (int i = t; i < n; i += 256) {
            const int d = dst[e0 + i];
            const int s = src[e0 + i];
            const int p = atomicAdd(&cur[d >> 7], 1);
            myseg[p] = ((uint_t)s << 7) | (uint_t)(d & 127);
        }
    } else {
        // ---- gemm role: MFMA, 4 waves x 16 cols, 4 row-tiles per wave ----
        const int gb  = blockIdx.x - NSPLIT;
        const int wv  = t >> 6;
        const int l   = t & 63;
        const int lr  = l & 15;
        const int lk  = l >> 4;
        const int col = wv * 16 + lr;
        const int r0  = gb * GEMM_ROWS;

        bf16x8 b0, b1;
#pragma unroll
        for (int j = 0; j < 8; ++j) {
            b0[j] = (short)f2bf(w[(lk * 8 + j) * F + col]);
            b1[j] = (short)f2bf(w[(32 + lk * 8 + j) * F + col]);
        }

#pragma unroll
        for (int tt = 0; tt < 4; ++tt) {
            const int r  = r0 + tt * 16 + lr;
            const int rl = min(r, N_NODES - 1);
            const float4 ha0 = *(const float4*)(h + (size_t)rl * F + lk * 8);
            const float4 ha1 = *(const float4*)(h + (size_t)rl * F + lk * 8 + 4);
            const float4 hb0 = *(const float4*)(h + (size_t)rl * F + 32 + lk * 8);
            const float4 hb1 = *(const float4*)(h + (size_t)rl * F + 32 + lk * 8 + 4);
            bf16x8 a0, a1;
            a0[0] = (short)f2bf(ha0.x); a0[1] = (short)f2bf(ha0.y);
            a0[2] = (short)f2bf(ha0.z); a0[3] = (short)f2bf(ha0.w);
            a0[4] = (short)f2bf(ha1.x); a0[5] = (short)f2bf(ha1.y);
            a0[6] = (short)f2bf(ha1.z); a0[7] = (short)f2bf(ha1.w);
            a1[0] = (short)f2bf(hb0.x); a1[1] = (short)f2bf(hb0.y);
            a1[2] = (short)f2bf(hb0.z); a1[3] = (short)f2bf(hb0.w);
            a1[4] = (short)f2bf(hb1.x); a1[5] = (short)f2bf(hb1.y);
            a1[6] = (short)f2bf(hb1.z); a1[7] = (short)f2bf(hb1.w);

            f32x4 acc = {0.f, 0.f, 0.f, 0.f};
            acc = __builtin_amdgcn_mfma_f32_16x16x32_bf16(a0, b0, acc, 0, 0, 0);
            acc = __builtin_amdgcn_mfma_f32_16x16x32_bf16(a1, b1, acc, 0, 0, 0);

#pragma unroll
            for (int i2 = 0; i2 < 4; ++i2) {
                const int m = r0 + tt * 16 + lk * 4 + i2;
                if (m < N_NODES)
                    hn[(size_t)m * F + col] = f2bf(acc[i2] * norm[m]);
            }
        }
    }
}

// ---------------------------------------------------------------------------
// Fused build+gather: one block (512 thr) per bucket of 128 dst nodes.
// Assemble the bucket's edge list from NSPLIT per-block slices (L2-hot) ->
// LDS count/scan -> bucket-local list -> register-accumulating gather
// (wave per node), fused post-scale, one store per output row.
// ---------------------------------------------------------------------------
__launch_bounds__(512)
__global__ void gather_build_kernel(const ushort_t* __restrict__ offtab,
                                    const uint_t* __restrict__ seg,
                                    const ushort_t* __restrict__ hn,
                                    const float* __restrict__ norm,
                                    float* __restrict__ out) {
    __shared__ uint_t ebuf[CAP];     // 9.7 KB packed records
    __shared__ int    lsrc[CAP];     // 9.7 KB bucket-local edge list (src ids)
    __shared__ int    cnt[NPB];
    __shared__ int    beg[NPB];
    __shared__ int    cur[NPB];
    __shared__ int    sc[NPB];
    __shared__ int    sstart[256];   // slice start within its segment
    __shared__ int    scn[256];      // slice-length scan (inclusive)

    const int b = blockIdx.x;
    const int t = threadIdx.x;

    // ---- slice ranges for this bucket (one per split block) ----
    int slen_v = 0, sstart_v = 0;
    if (t < NSPLIT) {
        const ushort_t* row = offtab + (size_t)t * (NB + 1);
        sstart_v = row[b];
        slen_v   = row[b + 1] - sstart_v;
    }
    if (t < 256) { sstart[t] = sstart_v; scn[t] = slen_v; }
    __syncthreads();

    // inclusive scan of slice lengths over 256 entries (threads t<256)
    int acc = slen_v;
#pragma unroll
    for (int off = 1; off < 256; off <<= 1) {
        int add = 0;
        if (t < 256 && t >= off) add = scn[t - off];
        __syncthreads();
        if (t < 256) { acc += add; scn[t] = acc; }
        __syncthreads();
    }
    const int n = min(scn[255], CAP);

    // ---- copy slices into ebuf (wave per slice, round-robin) ----
    const int wave = t >> 6;
    const int lane = t & 63;
    for (int s = wave; s < NSPLIT; s += 8) {
        const int base = scn[s] - (scn[s] - ((s > 0) ? scn[s - 1] : 0)); // exclusive
        const int len  = scn[s] - ((s > 0) ? scn[s - 1] : 0);
        const uint_t* sp = seg + (size_t)s * BLK_E + sstart[s];
        for (int j = lane; j < len; j += 64) {
            const int o = base + j;
            if (o < CAP) ebuf[o] = sp[j];
        }
    }
    __syncthreads();

    // ---- per-node count ----
    if (t < NPB) cnt[t] = 0;
    __syncthreads();
    for (int i = t; i < n; i += 512)
        atomicAdd(&cnt[ebuf[i] & 127u], 1);
    __syncthreads();

    // ---- Hillis-Steele inclusive scan over 128 counts ----
    int acc2 = (t < NPB) ? cnt[t] : 0;
    if (t < NPB) sc[t] = acc2;
    __syncthreads();
#pragma unroll
    for (int off = 1; off < NPB; off <<= 1) {
        int add = 0;
        if (t < NPB && t >= off) add = sc[t - off];
        __syncthreads();
        if (t < NPB) { acc2 += add; sc[t] = acc2; }
        __syncthreads();
    }
    if (t < NPB) {
        const int e = acc2 - cnt[t];
        beg[t] = e;
        cur[t] = e;
    }
    __syncthreads();

    // ---- place into bucket-local per-node lists ----
    for (int i = t; i < n; i += 512) {
        const uint_t e = ebuf[i];
        const int p = atomicAdd(&cur[e & 127u], 1);
        lsrc[p] = (int)(e >> 7);
    }
    __syncthreads();

    // ---- gather: wave w handles local nodes w, w+8, ... ----
    const int s = lane >> 4;   // edge slot
    const int c = lane & 15;   // col group: cols 4c..4c+3

    for (int ld = wave; ld < NPB; ld += 8) {
        const int node = b * NPB + ld;
        if (node >= N_NODES) break;

        const int bg = beg[ld];
        const int en = bg + cnt[ld];

        float a0 = 0.f, a1 = 0.f, a2 = 0.f, a3 = 0.f;
        int i = bg;
        for (; i + 7 < en; i += 8) {
            const int sA = lsrc[i + s];
            const int sB = lsrc[i + 4 + s];
            const uint2 vA = *(const uint2*)(hn + (size_t)sA * F + 4 * c);
            const uint2 vB = *(const uint2*)(hn + (size_t)sB * F + 4 * c);
            a0 += bflo(vA.x) + bflo(vB.x);
            a1 += bfhi(vA.x) + bfhi(vB.x);
            a2 += bflo(vA.y) + bflo(vB.y);
            a3 += bfhi(vA.y) + bfhi(vB.y);
        }
        for (; i < en; i += 4) {
            const int e = i + s;
            if (e < en) {
                const int sv = lsrc[e];
                const uint2 v = *(const uint2*)(hn + (size_t)sv * F + 4 * c);
                a0 += bflo(v.x);
                a1 += bfhi(v.x);
                a2 += bflo(v.y);
                a3 += bfhi(v.y);
            }
        }

        a0 += __shfl_xor(a0, 16); a0 += __shfl_xor(a0, 32);
        a1 += __shfl_xor(a1, 16); a1 += __shfl_xor(a1, 32);
        a2 += __shfl_xor(a2, 16); a2 += __shfl_xor(a2, 32);
        a3 += __shfl_xor(a3, 16); a3 += __shfl_xor(a3, 32);

        if (s == 0) {
            const float nv = norm[node];
            float4 r;
            r.x = a0 * nv; r.y = a1 * nv; r.z = a2 * nv; r.w = a3 * nv;
            *(float4*)(out + (size_t)node * F + 4 * c) = r;
        }
    }
}

extern "C" void kernel_launch(void* const* d_in, const int* in_sizes, int n_in,
                              void* d_out, int out_size, void* d_ws, size_t ws_size,
                              hipStream_t stream) {
    const float* h    = (const float*)d_in[0];
    const float* w    = (const float*)d_in[1];
    const float* norm = (const float*)d_in[2];
    const int*   src  = (const int*)d_in[3];
    const int*   dst  = (const int*)d_in[4];
    float* out = (float*)d_out;

    // Workspace layout (256-aligned chunks), total ~19.6 MB:
    char* ws = (char*)d_ws;
    ushort_t* hn     = (ushort_t*)ws;                        // 12,800,000 B
    uint_t*   seg    = (uint_t*)(ws + 12800000);             //  6,422,528 B (NSPLIT*BLK_E*4)
    ushort_t* offtab = (ushort_t*)(ws + 12800000 + 6422528); //    306,936 B (NSPLIT*(NB+1)*2)

    gemm_split_kernel<<<NSPLIT + NGEMM, 256, 0, stream>>>(
        h, w, norm, hn, src, dst, offtab, seg);

    gather_build_kernel<<<NB, 512, 0, stream>>>(offtab, seg, hn, norm, out);
}